// Round 5
// baseline (197.916 us; speedup 1.0000x reference)
//
#include <hip/hip_runtime.h>

// ---------------------------------------------------------------------------
// TripletLossWithHardMining  (B=4096, D=1024, fp32 in, fp32 scalar out)
//
//  K1 row_stats : wave-per-row; per-row constants; d_ap, d_an_row; bf16
//                 copies of a,p,n; init hard slots.
//  K2 gemm_mask : R9 (= R8 resubmit after infra failure; kernel re-audited:
//                 barrier uniformity, per-wave vmcnt FIFO, OOB, bank math).
//                 256x256-tile z-GEMM (z: A.N^T / A.P^T), 8 waves (2x4),
//                 per-wave 128x64 -> LDS bytes/FLOP 1.33x lower than 128².
//                 K-HALF PANEL pipeline: each K-tile stored as two contiguous
//                 256x32 panels (k0,k1) per matrix; phases consume k0 then k1
//                 UNIFORMLY across waves. Per K-tile:
//                   ph0 k0/im0-3 (stage A-k0 nxt) | ph1 k0/im4-7 (stage B-k0)
//                   -> vmcnt(4)+bar   [retires cur-k1, issued 2-3 phases ago]
//                   ph2 k1/im0-3 (stage A-k1) | ph3 k1/im4-7 (stage B-k1)
//                   -> vmcnt(4)+bar   [retires nxt-k0]
//                 NO vmcnt(0) in the loop; outstanding peaks at 8/wave;
//                 stages only write the non-read buffer. 4-slot XOR swizzle
//                 (slot = chunk ^ ((row>>1)&3)) on 64B panel rows reproduces
//                 the proven 0-conflict bank-group occupancy. setprio on MFMA.
//  K3 finalize  : d_an = mean(hard_n), d_pp = mean(hard_p, inf->0),
//                 loss = mean(relu(d_ap - 0.5*d_pp - 0.5*d_an + 1)).
//
//  Dead-ends (MfmaUtil pinned 26-29 across ALL of these -> bytes/FLOP bound,
//  not schedule/occupancy bound):
//   R4 barrier-free per-wave vmcnt(4):        184us, 15%
//   R5 fused 256x128 8-phase + vmcnt(0)/tile: 104us, 27%
//   R6 fused 256x128 4-phase counted:         107us, 26%
//   R7 unfused 128² 2-barrier, 3 blk/CU:      104us, 27%  (occ 27%, no gain)
//   R8 this kernel: container failed twice (infra; no test/compile signal)
// ---------------------------------------------------------------------------

#define NB 4096
#define DIM 1024
#define EPSF 1e-6f
#define D_EPS2 (1024.0f * 1e-6f * 1e-6f)

#define BT 256           // block tile (rows of A and rows of B/cols of C)
#define KHALF 32         // k-half panel width (elems); K-tile = 64

typedef __bf16  bf16x8 __attribute__((ext_vector_type(8)));
typedef float   f32x4  __attribute__((ext_vector_type(4)));

__device__ __forceinline__ unsigned short f2bf(float x) {
    unsigned u = __float_as_uint(x);
    u += 0x7FFFu + ((u >> 16) & 1u);   // round-to-nearest-even
    return (unsigned short)(u >> 16);
}

// async 16B/lane global->LDS; lds base wave-uniform, data lands at base+lane*16
__device__ __forceinline__ void g2l16(const unsigned short* g, unsigned short* l) {
    __builtin_amdgcn_global_load_lds(
        (const __attribute__((address_space(1))) unsigned int*)g,
        (__attribute__((address_space(3))) unsigned int*)l, 16, 0, 0);
}

// stats layout (NB-float slots):
// 0: base_a[i] = |a_i|^2 + 2e*sum_a + D*e^2
// 1: cn[j]     = |n_j|^2 - 2e*sum_n
// 2: cp[j]     = |p_j|^2 - 2e*sum_p
// 3: d_ap   4: d_an_row   5: hard_n bits   6: hard_p bits

// wave-per-row: 1024 blocks x 4 waves; lane handles 4 float4 chunks per matrix
__global__ __launch_bounds__(256) void row_stats_kernel(
    const float* __restrict__ a, const float* __restrict__ p,
    const float* __restrict__ n,
    unsigned short* __restrict__ abf, unsigned short* __restrict__ pbf,
    unsigned short* __restrict__ nbf, float* __restrict__ stats)
{
    const int t    = threadIdx.x;
    const int wave = t >> 6, lane = t & 63;
    const int row  = blockIdx.x * 4 + wave;
    const size_t base = (size_t)row * DIM;

    const float4* a4 = (const float4*)(a + base);
    const float4* p4 = (const float4*)(p + base);
    const float4* n4 = (const float4*)(n + base);

    float v[8] = {0,0,0,0,0,0,0,0};   // sa qa sp qp sn qn dap2 dan2
#pragma unroll
    for (int c = 0; c < 4; c++) {
        const int idx = c * 64 + lane;
        const float4 va = a4[idx];
        const float4 vp = p4[idx];
        const float4 vn = n4[idx];
        const float fa[4] = {va.x, va.y, va.z, va.w};
        const float fp[4] = {vp.x, vp.y, vp.z, vp.w};
        const float fn[4] = {vn.x, vn.y, vn.z, vn.w};
#pragma unroll
        for (int e = 0; e < 4; e++) {
            v[0] += fa[e];           v[1] += fa[e] * fa[e];
            v[2] += fp[e];           v[3] += fp[e] * fp[e];
            v[4] += fn[e];           v[5] += fn[e] * fn[e];
            float dp = fa[e] - fp[e] + EPSF;  v[6] += dp * dp;
            float dn = fa[e] - fn[e] + EPSF;  v[7] += dn * dn;
        }
        ushort4 ba, bp, bn;
        ba.x = f2bf(fa[0]); ba.y = f2bf(fa[1]); ba.z = f2bf(fa[2]); ba.w = f2bf(fa[3]);
        bp.x = f2bf(fp[0]); bp.y = f2bf(fp[1]); bp.z = f2bf(fp[2]); bp.w = f2bf(fp[3]);
        bn.x = f2bf(fn[0]); bn.y = f2bf(fn[1]); bn.z = f2bf(fn[2]); bn.w = f2bf(fn[3]);
        ((ushort4*)(abf + base))[idx] = ba;
        ((ushort4*)(pbf + base))[idx] = bp;
        ((ushort4*)(nbf + base))[idx] = bn;
    }

#pragma unroll
    for (int m = 32; m >= 1; m >>= 1)
#pragma unroll
        for (int q = 0; q < 8; q++) v[q] += __shfl_xor(v[q], m);

    if (lane == 0) {
        stats[0 * NB + row] = v[1] + 2.0f * EPSF * v[0] + D_EPS2;  // base_a
        stats[1 * NB + row] = v[5] - 2.0f * EPSF * v[4];           // cn
        stats[2 * NB + row] = v[3] - 2.0f * EPSF * v[2];           // cp
        stats[3 * NB + row] = sqrtf(v[6]);                         // d_ap
        stats[4 * NB + row] = sqrtf(v[7]);                         // d_an_row
        ((unsigned*)stats)[5 * NB + row] = 0u;                     // hard_n
        ((unsigned*)stats)[6 * NB + row] = 0x7f800000u;            // hard_p
    }
}

// 512 blocks (1D): swz -> (z, j, i); z=0: A.N^T (hard_n), z=1: A.P^T (hard_p)
__global__ __launch_bounds__(512, 2) void gemm_mask_kernel(
    const unsigned short* __restrict__ Abf,
    const unsigned short* __restrict__ Nbf,
    const unsigned short* __restrict__ Pbf,
    float* __restrict__ stats)
{
    // T1: flat%8 = XCD; each XCD owns a contiguous 64-block chunk.
    // 512%8==0 -> bijective. XCD 0-3 run z=0 (N), 4-7 run z=1 (P).
    const int flat = (int)blockIdx.x;               // 0..511
    const int swz  = (flat & 7) * 64 + (flat >> 3);
    const int bz   = swz >> 8;                      // 0 = N, 1 = P
    const int rem  = swz & 255;                     // 16 i x 16 j, i fastest
    const int i0   = (rem & 15) * BT;
    const int j0   = (rem >> 4) * BT;

    const unsigned short* __restrict__ Bbf = bz ? Pbf : Nbf;

    // k-half panels: [buf][khalf][256 rows x 32 elems] = 16 KB each
    __shared__ unsigned short sA[2][2][BT * KHALF];   // 64 KB
    __shared__ unsigned short sB[2][2][BT * KHALF];   // 64 KB -> 128 KB total

    const int t    = threadIdx.x;
    const int wave = t >> 6, lane = t & 63;
    const int wr   = wave >> 2, wc = wave & 3;        // 2 x 4 wave grid
    const int quad = lane >> 4, lrow = lane & 15;

    // ---- staging: one g2l round = 512 thr x 16 B = 8 KB = 128 panel rows.
    // thread t -> row srow = t>>2 (+128*g), slot = t&3; physical slot s
    // holds logical 16B-chunk s ^ ((row>>1)&3)  (pre-swizzled global src,
    // linear LDS dest; (row>>1)&3 is g-invariant since 128/2 % 4 == 0).
    const int srow = t >> 2;                           // 0..127
    const int gch  = ((t & 3) ^ ((srow >> 1) & 3)) * 8;
    const unsigned short* gA = Abf + (size_t)(i0 + srow) * DIM + gch;
    const unsigned short* gB = Bbf + (size_t)(j0 + srow) * DIM + gch;
    const int lbase = wave * 512;                      // elems; +g*4096

    // ---- fragment read: logical chunk quad, physical quad^((lrow>>1)&3)
    const int rsw  = (quad ^ ((lrow >> 1) & 3)) * 8;
    const int arow = wr * 128 + lrow;                  // + im*16
    const int brow = wc * 64 + lrow;                   // + jn*16

    f32x4 acc[8][4];
#pragma unroll
    for (int im = 0; im < 8; im++)
#pragma unroll
        for (int jn = 0; jn < 4; jn++)
            acc[im][jn] = (f32x4)(0.0f);

// stage one k-half panel (2 x g2l16) of tile starting at elem KT into buf NBUF
#define STG_A(NBUF, KS, KT)                                                   \
    g2l16(gA + (size_t)(KT) + (KS) * KHALF,            &sA[NBUF][KS][lbase]); \
    g2l16(gA + (size_t)(KT) + (KS) * KHALF + (size_t)128 * DIM,               \
          &sA[NBUF][KS][4096 + lbase]);

#define STG_B(NBUF, KS, KT)                                                   \
    g2l16(gB + (size_t)(KT) + (KS) * KHALF,            &sB[NBUF][KS][lbase]); \
    g2l16(gB + (size_t)(KT) + (KS) * KHALF + (size_t)128 * DIM,               \
          &sB[NBUF][KS][4096 + lbase]);

#define LDA4(DST, BUF, KS, IMB)                                               \
    _Pragma("unroll")                                                         \
    for (int m = 0; m < 4; m++)                                               \
        DST[m] = *(const bf16x8*)&sA[BUF][KS][(arow + ((IMB) + m) * 16) * KHALF + rsw];

#define LDB4(DST, BUF, KS)                                                    \
    _Pragma("unroll")                                                         \
    for (int j = 0; j < 4; j++)                                               \
        DST[j] = *(const bf16x8*)&sB[BUF][KS][(brow + j * 16) * KHALF + rsw];

#define MM16(IMB, AF, BF)                                                     \
    __builtin_amdgcn_s_setprio(1);                                            \
    _Pragma("unroll")                                                         \
    for (int m = 0; m < 4; m++)                                               \
        _Pragma("unroll")                                                     \
        for (int j = 0; j < 4; j++)                                           \
            acc[(IMB) + m][j] = __builtin_amdgcn_mfma_f32_16x16x32_bf16(      \
                AF[m], BF[j], acc[(IMB) + m][j], 0, 0, 0);                    \
    __builtin_amdgcn_s_setprio(0);

#define BAR()     __builtin_amdgcn_s_barrier()
#define VMCNT(N)  asm volatile("s_waitcnt vmcnt(" #N ")" ::: "memory")

    // prologue: stage T0 (order: A-k0, B-k0, A-k1, B-k1) -> retire k0 pair
    STG_A(0, 0, 0);
    STG_B(0, 0, 0);
    STG_A(0, 1, 0);
    STG_B(0, 1, 0);
    VMCNT(4);            // A-k0,B-k0 landed; k1 pair (4 loads) in flight
    BAR();

    // main loop: tiles 0..14 (peel 15). Per-wave VMEM FIFO:
    //  end-ph1: [cur-k1(4), A-k0n(2), B-k0n(2)] -> vmcnt(4) retires cur-k1
    //  end-ph3: [k0n(4), A-k1n(2), B-k1n(2)]    -> vmcnt(4) retires k0n
#pragma unroll 1
    for (int kt15 = 0; kt15 < 15; ++kt15) {
        const int cur = kt15 & 1, nxt = cur ^ 1;
        const int kn  = (kt15 + 1) * 2 * KHALF;
        bf16x8 af[4], bf[4];
        // ph0: k0, im0-3 ; stage A-k0(next)
        LDA4(af, cur, 0, 0);
        LDB4(bf, cur, 0);
        STG_A(nxt, 0, kn);
        MM16(0, af, bf);
        // ph1: k0, im4-7 ; stage B-k0(next)
        LDA4(af, cur, 0, 4);
        STG_B(nxt, 0, kn);
        MM16(4, af, bf);
        VMCNT(4);
        BAR();
        // ph2: k1, im0-3 ; stage A-k1(next)
        LDA4(af, cur, 1, 0);
        LDB4(bf, cur, 1);
        STG_A(nxt, 1, kn);
        MM16(0, af, bf);
        // ph3: k1, im4-7 ; stage B-k1(next)
        LDA4(af, cur, 1, 4);
        STG_B(nxt, 1, kn);
        MM16(4, af, bf);
        VMCNT(4);
        BAR();
    }

    // peeled tile 15 (buf 1): no staging; k1 pair still in flight at entry
    {
        bf16x8 af[4], bf[4];
        LDA4(af, 1, 0, 0);
        LDB4(bf, 1, 0);
        MM16(0, af, bf);
        LDA4(af, 1, 0, 4);
        MM16(4, af, bf);
        VMCNT(0);          // one-time: T15-k1 panels must land
        BAR();
        LDA4(af, 1, 1, 0);
        LDB4(bf, 1, 1);
        MM16(0, af, bf);
        LDA4(af, 1, 1, 4);
        MM16(4, af, bf);
    }

#undef BAR
#undef VMCNT
#undef MM16
#undef LDB4
#undef LDA4
#undef STG_B
#undef STG_A

    // epilogue: distances + mask + row reduce + atomic (one matrix per block)
    const float* __restrict__ base_a = stats + 0 * NB;
    const float* __restrict__ cv     = stats + (bz ? 2 : 1) * NB;  // cp : cn
    const float* __restrict__ cut_v  = stats + (bz ? 4 : 3) * NB;  // d_an : d_ap
    unsigned* __restrict__ hard = ((unsigned*)stats) + (bz ? 6 : 5) * NB;

#pragma unroll
    for (int im = 0; im < 8; im++) {
#pragma unroll
        for (int r = 0; r < 4; r++) {
            const int gi = i0 + wr * 128 + im * 16 + quad * 4 + r;
            const float cut = cut_v[gi];
            const float bi  = base_a[gi];
            if (bz == 0) {
                // hardest negative: max d over {d < d_ap[i]}
                float best = 0.0f;
#pragma unroll
                for (int jn = 0; jn < 4; jn++) {
                    const int gj = j0 + wc * 64 + jn * 16 + lrow;
                    const float d = sqrtf(fmaxf(bi + cv[gj] - 2.0f * acc[im][jn][r], 0.0f));
                    if (d < cut && d > best) best = d;
                }
#pragma unroll
                for (int m = 1; m < 16; m <<= 1)
                    best = fmaxf(best, __shfl_xor(best, m));
                if (lrow == 0) {
                    const unsigned b_ = __float_as_uint(best);
                    if (b_ != 0u) atomicMax(hard + gi, b_);
                }
            } else {
                // hardest positive: min d over {d > d_an_row[i]}
                float best = __uint_as_float(0x7f800000u);
#pragma unroll
                for (int jn = 0; jn < 4; jn++) {
                    const int gj = j0 + wc * 64 + jn * 16 + lrow;
                    const float d = sqrtf(fmaxf(bi + cv[gj] - 2.0f * acc[im][jn][r], 0.0f));
                    if (d > cut && d < best) best = d;
                }
#pragma unroll
                for (int m = 1; m < 16; m <<= 1)
                    best = fminf(best, __shfl_xor(best, m));
                if (lrow == 0) {
                    const unsigned b_ = __float_as_uint(best);
                    if (b_ != 0x7f800000u) atomicMin(hard + gi, b_);
                }
            }
        }
    }
}

__global__ __launch_bounds__(1024) void finalize_kernel(
    const float* __restrict__ stats, float* __restrict__ out)
{
    const unsigned* hard_n = ((const unsigned*)stats) + 5 * NB;
    const unsigned* hard_p = ((const unsigned*)stats) + 6 * NB;
    const float*    d_ap   = stats + 3 * NB;
    const int t = threadIdx.x;
    const int wave = t >> 6, lane = t & 63;
    __shared__ float pn[16], pp[16];
    __shared__ float s_dan, s_dpp;

    float sn = 0.0f, sp = 0.0f;
    for (int i = t; i < NB; i += 1024) {
        sn += __uint_as_float(hard_n[i]);
        const unsigned hp = hard_p[i];
        if (hp != 0x7f800000u) sp += __uint_as_float(hp);
    }
#pragma unroll
    for (int m = 32; m >= 1; m >>= 1) {
        sn += __shfl_xor(sn, m);
        sp += __shfl_xor(sp, m);
    }
    if (lane == 0) { pn[wave] = sn; pp[wave] = sp; }
    __syncthreads();
    if (t == 0) {
        float an = 0.0f, ap = 0.0f;
#pragma unroll
        for (int w = 0; w < 16; w++) { an += pn[w]; ap += pp[w]; }
        s_dan = an / (float)NB;
        s_dpp = ap / (float)NB;
    }
    __syncthreads();
    const float dan = s_dan, dpp = s_dpp;

    float accv = 0.0f;
    for (int i = t; i < NB; i += 1024)
        accv += fmaxf(d_ap[i] - 0.5f * dpp - 0.5f * dan + 1.0f, 0.0f);
#pragma unroll
    for (int m = 32; m >= 1; m >>= 1) accv += __shfl_xor(accv, m);
    if (lane == 0) pn[wave] = accv;
    __syncthreads();
    if (t == 0) {
        float s = 0.0f;
#pragma unroll
        for (int w = 0; w < 16; w++) s += pn[w];
        out[0] = s / (float)NB;
    }
}

extern "C" void kernel_launch(void* const* d_in, const int* in_sizes, int n_in,
                              void* d_out, int out_size, void* d_ws, size_t ws_size,
                              hipStream_t stream) {
    const float* a = (const float*)d_in[0];
    const float* p = (const float*)d_in[1];
    const float* n = (const float*)d_in[2];
    float* out = (float*)d_out;

    // ws layout: abf | pbf | nbf | stats(7*NB floats)  => ~25.3 MB
    unsigned short* abf = (unsigned short*)d_ws;
    unsigned short* pbf = abf + (size_t)NB * DIM;
    unsigned short* nbf = pbf + (size_t)NB * DIM;
    float* stats = (float*)(nbf + (size_t)NB * DIM);

    row_stats_kernel<<<NB / 4, 256, 0, stream>>>(a, p, n, abf, pbf, nbf, stats);

    // 2 GEMMs x (16x16) 256² tiles, flattened 1D for the XCD swizzle
    gemm_mask_kernel<<<512, 512, 0, stream>>>(abf, nbf, pbf, stats);

    finalize_kernel<<<1, 1024, 0, stream>>>(stats, out);
}